// Round 9
// baseline (30.799 us; speedup 1.0000x reference)
//
#include <hip/hip_runtime.h>
#include <stdint.h>

typedef __attribute__((ext_vector_type(8))) short short8;
typedef __attribute__((ext_vector_type(4))) float f32x4;

namespace {
constexpr int   kN     = 50;
constexpr int   kD     = 128;
constexpr float kNeg   = -9.0e15f;
constexpr float kSlope = 0.2f;
constexpr int   HS16   = 136;   // Hhi/Hlo stride (shorts), 16B-aligned rows, 2-way max banks
constexpr int   SS     = 68;    // Sa stride (f32)
constexpr int   AS     = 36;    // At stride (shorts): [j][iL], 8B-aligned ushort4 reads
constexpr int   ADS    = 52;    // adj byte-stride
}

union Pack8 { uint32_t u[4]; short8 s; };

__global__ __launch_bounds__(512)
void gat_v9_kernel(const float* __restrict__ hidden,
                   const int*   __restrict__ adj,
                   const float* __restrict__ a0,
                   const float* __restrict__ a1,
                   const float* __restrict__ a2,
                   const float* __restrict__ a3,
                   float* __restrict__ out)
{
    __shared__ unsigned short Hhi[64 * HS16];   // 17.4 KB bf16 hi(H), rows>=50 zero
    __shared__ unsigned short Hlo[64 * HS16];   // 17.4 KB bf16 lo(H)
    __shared__ float          Sa [32 * SS];     //  8.7 KB summed selected scores (atomicAdd)
    __shared__ unsigned short At [64 * AS];     //  4.6 KB attn bf16-RN, [j][i-local]
    __shared__ unsigned char  Ad [kN * ADS];    //  2.6 KB adj bytes
    // total 50.7 KB -> 3 blocks/CU residency

    const int b    = blockIdx.x >> 1;
    const int ih   = blockIdx.x & 1;            // i-half: rows 0..31 / 32..49
    const int tid  = threadIdx.x;
    const int lane = tid & 63;
    const int wid  = __builtin_amdgcn_readfirstlane(tid >> 6);
    const int g    = lane >> 4;
    const int f    = lane & 15;

    const float* __restrict__ hb   = hidden + (size_t)b * (kN * kD);
    const int*   __restrict__ adjb = adj    + (size_t)b * (kN * kN);
    float*       __restrict__ outb = out    + (size_t)b * (kN * kD);

    // ---------------- phase 1: zero Sa (ALL 544 float4s), stage adj bytes + H hi/lo ----------------
    for (int idx = tid; idx < 544; idx += 512)
        reinterpret_cast<float4*>(Sa)[idx] = make_float4(0.f, 0.f, 0.f, 0.f);

    for (int idx = tid; idx < 625; idx += 512) {          // 2500 ints as int4
        const int4 v = reinterpret_cast<const int4*>(adjb)[idx];
        const int e = 4 * idx;
        const int vv[4] = {v.x, v.y, v.z, v.w};
        #pragma unroll
        for (int p = 0; p < 4; ++p) {
            const int ee  = e + p;
            const int row = ee / kN;
            const int col = ee - kN * row;
            Ad[row * ADS + col] = (unsigned char)vv[p];
        }
    }

    const float4* hg = reinterpret_cast<const float4*>(hb);
    #pragma unroll
    for (int it4 = 0; it4 < 4; ++it4) {
        const int idx = tid + it4 * 512;        // 0..2047 over 64 rows x 32 float4
        const int j   = idx >> 5;
        const int d4  = idx & 31;
        float4 v = make_float4(0.f, 0.f, 0.f, 0.f);
        if (j < kN) v = hg[j * 32 + d4];

        const uint32_t h0 = __float_as_uint(v.x) & 0xffff0000u;
        const uint32_t h1 = __float_as_uint(v.y) & 0xffff0000u;
        const uint32_t h2 = __float_as_uint(v.z) & 0xffff0000u;
        const uint32_t h3 = __float_as_uint(v.w) & 0xffff0000u;
        uint2 hiw;
        hiw.x = h1 | (h0 >> 16);
        hiw.y = h3 | (h2 >> 16);
        const float r0 = v.x - __uint_as_float(h0);
        const float r1 = v.y - __uint_as_float(h1);
        const float r2 = v.z - __uint_as_float(h2);
        const float r3 = v.w - __uint_as_float(h3);
        uint2 low;
        low.x = (__float_as_uint(r1) & 0xffff0000u) | (__float_as_uint(r0) >> 16);
        low.y = (__float_as_uint(r3) & 0xffff0000u) | (__float_as_uint(r2) >> 16);
        *reinterpret_cast<uint2*>(&Hhi[j * HS16 + 4 * d4]) = hiw;
        *reinterpret_cast<uint2*>(&Hlo[j * HS16 + 4 * d4]) = low;
    }
    __syncthreads();

    // ---------------- phase 2: scores via MFMA; wave = (itL, K-quarter) ----------------
    {
        const int itL = wid & 1;
        const int kq  = wid >> 1;               // 0..3, one 32-wide K slice per wave
        const int i0  = 32 * ih + 16 * itL;
        const int irow = (i0 + f < kN) ? (i0 + f) : (kN - 1);
        const int dofs = 32 * kq + 8 * g;

        // A-side: h_i f32 from global (L2-hot), per-lane row irow
        const float4 hA0 = *reinterpret_cast<const float4*>(hb + irow * kD + dofs);
        const float4 hA1 = *reinterpret_cast<const float4*>(hb + irow * kD + dofs + 4);
        const float ha[8] = {hA0.x, hA0.y, hA0.z, hA0.w, hA1.x, hA1.y, hA1.z, hA1.w};

        // hoisted q_k = h_i * a_k packing (hi/lo bf16), once per wave
        const float* __restrict__ aks[4] = {a0, a1, a2, a3};
        short8 qh[4], ql[4];
        #pragma unroll
        for (int k = 0; k < 4; ++k) {
            const float4 av0 = *reinterpret_cast<const float4*>(aks[k] + dofs);
            const float4 av1 = *reinterpret_cast<const float4*>(aks[k] + dofs + 4);
            const float aa[8] = {av0.x, av0.y, av0.z, av0.w, av1.x, av1.y, av1.z, av1.w};
            Pack8 ph, pl;
            #pragma unroll
            for (int p = 0; p < 4; ++p) {
                const float q0 = ha[2 * p]     * aa[2 * p];
                const float q1 = ha[2 * p + 1] * aa[2 * p + 1];
                const uint32_t b0 = __float_as_uint(q0) & 0xffff0000u;
                const uint32_t b1 = __float_as_uint(q1) & 0xffff0000u;
                ph.u[p] = b1 | (b0 >> 16);
                const float s0 = q0 - __uint_as_float(b0);
                const float s1 = q1 - __uint_as_float(b1);
                pl.u[p] = (__float_as_uint(s1) & 0xffff0000u) | (__float_as_uint(s0) >> 16);
            }
            qh[k] = ph.s;
            ql[k] = pl.s;
        }

        f32x4 acc[4][4];                        // [jt][k]
        #pragma unroll
        for (int jt = 0; jt < 4; ++jt)
            #pragma unroll
            for (int k = 0; k < 4; ++k) acc[jt][k] = (f32x4){0.f, 0.f, 0.f, 0.f};

        #pragma unroll
        for (int jt = 0; jt < 4; ++jt) {
            const int jrow = 16 * jt + f;       // rows>=50 zeroed
            const short8 bh = *reinterpret_cast<const short8*>(&Hhi[jrow * HS16 + dofs]);
            const short8 bl = *reinterpret_cast<const short8*>(&Hlo[jrow * HS16 + dofs]);
            #pragma unroll
            for (int k = 0; k < 4; ++k) {
                acc[jt][k] = __builtin_amdgcn_mfma_f32_16x16x32_bf16(qh[k], bh, acc[jt][k], 0, 0, 0);
                acc[jt][k] = __builtin_amdgcn_mfma_f32_16x16x32_bf16(qh[k], bl, acc[jt][k], 0, 0, 0);
                acc[jt][k] = __builtin_amdgcn_mfma_f32_16x16x32_bf16(ql[k], bh, acc[jt][k], 0, 0, 0);
            }
        }

        // epilogue: select on the K-partial (commutes with K-sum), atomicAdd into Sa
        #pragma unroll
        for (int jt = 0; jt < 4; ++jt) {
            const int j = 16 * jt + f;
            if (j < kN) {
                #pragma unroll
                for (int reg = 0; reg < 4; ++reg) {
                    const int iL = 16 * itL + 4 * g + reg;
                    const int ii = 32 * ih + iL;
                    if (ii < kN) {
                        const int kv = Ad[ii * ADS + j];
                        if (kv >= 1 && kv <= 4) {
                            const float val = (kv == 1) ? acc[jt][0][reg]
                                            : (kv == 2) ? acc[jt][1][reg]
                                            : (kv == 3) ? acc[jt][2][reg]
                                            :             acc[jt][3][reg];
                            atomicAdd(&Sa[iL * SS + j], val);
                        }
                    }
                }
            }
        }
    }
    __syncthreads();

    // ---------------- phase 3: leaky+mask+softmax (wave -> 4 contiguous rows) ----------------
    {
        const int icount = ih ? (kN - 32) : 32;      // 18 or 32
        #pragma unroll
        for (int t = 0; t < 4; ++t) {
            const int rL = 4 * wid + t;
            if (rL < icount) {
                const int ii = 32 * ih + rL;
                int kv = 0;
                if (lane < kN) kv = Ad[ii * ADS + lane];
                float s = kNeg;
                if (kv >= 1 && kv <= 4) {
                    const float x = Sa[rL * SS + lane];
                    s = (x > 0.f) ? x : kSlope * x;
                }
                float m = s;
                #pragma unroll
                for (int o = 32; o; o >>= 1) m = fmaxf(m, __shfl_xor(m, o));
                const float e = (lane < kN) ? __expf(s - m) : 0.f;  // all-masked row -> uniform (matches ref)
                float ts = e;
                #pragma unroll
                for (int o = 32; o; o >>= 1) ts += __shfl_xor(ts, o);
                uint32_t u = __float_as_uint(e / ts);
                u += 0x7fffu + ((u >> 16) & 1u);     // round-to-nearest bf16
                if (lane < kN) At[lane * AS + rL] = (unsigned short)(u >> 16);
            }
        }
    }
    __syncthreads();

    // ---------------- phase 4: PV fp32; wave = (itL, d-quarter); h from global ----------------
    {
        const int itL = wid & 1;
        const int dq  = wid >> 1;               // 0..3
        const int i0L = 16 * itL;
        const int db  = 32 * dq + 2 * f;

        float2 o0 = {0.f, 0.f}, o1 = o0, o2 = o0, o3 = o0;
        #pragma unroll 5
        for (int j = 0; j < kN; ++j) {
            const float2  hv = *reinterpret_cast<const float2*>(hb + j * kD + db);
            const ushort4 a4 = *reinterpret_cast<const ushort4*>(&At[j * AS + i0L + 4 * g]);
            const float av0 = __uint_as_float(((uint32_t)a4.x) << 16);
            const float av1 = __uint_as_float(((uint32_t)a4.y) << 16);
            const float av2 = __uint_as_float(((uint32_t)a4.z) << 16);
            const float av3 = __uint_as_float(((uint32_t)a4.w) << 16);
            o0.x += av0 * hv.x; o0.y += av0 * hv.y;
            o1.x += av1 * hv.x; o1.y += av1 * hv.y;
            o2.x += av2 * hv.x; o2.y += av2 * hv.y;
            o3.x += av3 * hv.x; o3.y += av3 * hv.y;
        }
        const int iiB = 32 * ih + i0L + 4 * g;
        if (iiB + 0 < kN) *reinterpret_cast<float2*>(&outb[(iiB + 0) * kD + db]) = o0;
        if (iiB + 1 < kN) *reinterpret_cast<float2*>(&outb[(iiB + 1) * kD + db]) = o1;
        if (iiB + 2 < kN) *reinterpret_cast<float2*>(&outb[(iiB + 2) * kD + db]) = o2;
        if (iiB + 3 < kN) *reinterpret_cast<float2*>(&outb[(iiB + 3) * kD + db]) = o3;
    }
}

extern "C" void kernel_launch(void* const* d_in, const int* in_sizes, int n_in,
                              void* d_out, int out_size, void* d_ws, size_t ws_size,
                              hipStream_t stream) {
    const float* hidden = reinterpret_cast<const float*>(d_in[0]);
    const int*   adjp   = reinterpret_cast<const int*>(d_in[1]);
    const float* a0     = reinterpret_cast<const float*>(d_in[2]);
    const float* a1     = reinterpret_cast<const float*>(d_in[3]);
    const float* a2     = reinterpret_cast<const float*>(d_in[4]);
    const float* a3     = reinterpret_cast<const float*>(d_in[5]);
    float*       outp   = reinterpret_cast<float*>(d_out);

    gat_v9_kernel<<<dim3(512), dim3(512), 0, stream>>>(
        hidden, adjp, a0, a1, a2, a3, outp);
}

// Round 10
// 18.333 us; speedup vs baseline: 1.6799x; 1.6799x over previous
//
#include <hip/hip_runtime.h>
#include <stdint.h>

typedef __attribute__((ext_vector_type(8))) short short8;
typedef __attribute__((ext_vector_type(4))) float f32x4;

namespace {
constexpr int   kN     = 50;
constexpr int   kD     = 128;
constexpr float kNeg   = -9.0e15f;
constexpr float kSlope = 0.2f;
constexpr int   HS32   = 132;   // Hf stride (f32): 132%32=4 -> 2-way max on strided b128
constexpr int   HS16   = 136;   // Hhi/Hlo stride (shorts): 68%32=4 -> 2-way max
constexpr int   ADS    = 52;    // adj byte stride
constexpr int   PS     = 20;    // Pw stride (shorts) per j-row: 10-bank stride, <=4-way b16
}

union Pack8 { uint32_t u[4]; short8 s; };

__global__ __launch_bounds__(256)
void gat_v10_kernel(const float* __restrict__ hidden,
                    const int*   __restrict__ adj,
                    const float* __restrict__ a0,
                    const float* __restrict__ a1,
                    const float* __restrict__ a2,
                    const float* __restrict__ a3,
                    float* __restrict__ out)
{
    __shared__ float          Hf [kN * HS32];   // 26.4 KB f32 H (A-side + PV)
    __shared__ unsigned short Hhi[64 * HS16];   // 17.4 KB bf16 hi(H), rows>=50 zero
    __shared__ unsigned short Hlo[64 * HS16];   // 17.4 KB bf16 lo(H)
    __shared__ unsigned char  Ad [kN * ADS];    //  2.6 KB adj bytes
    __shared__ unsigned short Pw [4][64 * PS];  // 10.0 KB wave-private P, [j][row-local] bf16
    // total ~73.8 KB

    const int b    = blockIdx.x;
    const int tid  = threadIdx.x;
    const int lane = tid & 63;
    const int wid  = __builtin_amdgcn_readfirstlane(tid >> 6);  // 0..3 = i-tile
    const int g    = lane >> 4;
    const int f    = lane & 15;

    const float* __restrict__ hb   = hidden + (size_t)b * (kN * kD);
    const int*   __restrict__ adjb = adj    + (size_t)b * (kN * kN);
    float*       __restrict__ outb = out    + (size_t)b * (kN * kD);

    // ---------------- phase 1: stage Hf + H hi/lo + adj bytes (ONE barrier after) ----------------
    const float4* hg = reinterpret_cast<const float4*>(hb);
    #pragma unroll
    for (int it8 = 0; it8 < 8; ++it8) {
        const int idx = tid + it8 * 256;        // 0..2047 over 64 rows x 32 float4
        const int j   = idx >> 5;
        const int d4  = idx & 31;
        float4 v = make_float4(0.f, 0.f, 0.f, 0.f);
        if (j < kN) v = hg[j * 32 + d4];

        const uint32_t h0 = __float_as_uint(v.x) & 0xffff0000u;
        const uint32_t h1 = __float_as_uint(v.y) & 0xffff0000u;
        const uint32_t h2 = __float_as_uint(v.z) & 0xffff0000u;
        const uint32_t h3 = __float_as_uint(v.w) & 0xffff0000u;
        uint2 hiw;
        hiw.x = h1 | (h0 >> 16);
        hiw.y = h3 | (h2 >> 16);
        const float r0 = v.x - __uint_as_float(h0);
        const float r1 = v.y - __uint_as_float(h1);
        const float r2 = v.z - __uint_as_float(h2);
        const float r3 = v.w - __uint_as_float(h3);
        uint2 low;
        low.x = (__float_as_uint(r1) & 0xffff0000u) | (__float_as_uint(r0) >> 16);
        low.y = (__float_as_uint(r3) & 0xffff0000u) | (__float_as_uint(r2) >> 16);
        *reinterpret_cast<uint2*>(&Hhi[j * HS16 + 4 * d4]) = hiw;
        *reinterpret_cast<uint2*>(&Hlo[j * HS16 + 4 * d4]) = low;
        if (j < kN) *reinterpret_cast<float4*>(&Hf[j * HS32 + 4 * d4]) = v;
    }
    for (int idx = tid; idx < 625; idx += 256) {          // 2500 ints as int4
        const int4 v = reinterpret_cast<const int4*>(adjb)[idx];
        const int e = 4 * idx;
        const int vv[4] = {v.x, v.y, v.z, v.w};
        #pragma unroll
        for (int p = 0; p < 4; ++p) {
            const int ee  = e + p;
            const int row = ee / kN;
            const int col = ee - kN * row;
            Ad[row * ADS + col] = (unsigned char)vv[p];
        }
    }
    __syncthreads();   // the ONLY barrier

    // ---------------- phase 2: scores via MFMA; wave owns i-tile [i0, i0+16) ----------------
    const int i0   = 16 * wid;
    const int irow = (i0 + f < kN) ? (i0 + f) : (kN - 1);   // clamp; garbage rows discarded

    f32x4 acc[4][4];                            // [jt][rel]
    #pragma unroll
    for (int jt = 0; jt < 4; ++jt)
        #pragma unroll
        for (int k = 0; k < 4; ++k) acc[jt][k] = (f32x4){0.f, 0.f, 0.f, 0.f};

    const float* __restrict__ aks[4] = {a0, a1, a2, a3};

    #pragma unroll
    for (int ksl = 0; ksl < 4; ++ksl) {
        const int dofs = 32 * ksl + 8 * g;

        // A-side: h_i f32 from Hf (per-lane row irow), 2-way max banks
        const float4 hA0 = *reinterpret_cast<const float4*>(&Hf[irow * HS32 + dofs]);
        const float4 hA1 = *reinterpret_cast<const float4*>(&Hf[irow * HS32 + dofs + 4]);
        const float ha[8] = {hA0.x, hA0.y, hA0.z, hA0.w, hA1.x, hA1.y, hA1.z, hA1.w};

        // q_k = h_i * a_k, hi/lo bf16 packing (a_k from global, L1-hot broadcast)
        short8 qh[4], ql[4];
        #pragma unroll
        for (int k = 0; k < 4; ++k) {
            const float4 av0 = *reinterpret_cast<const float4*>(aks[k] + dofs);
            const float4 av1 = *reinterpret_cast<const float4*>(aks[k] + dofs + 4);
            const float aa[8] = {av0.x, av0.y, av0.z, av0.w, av1.x, av1.y, av1.z, av1.w};
            Pack8 ph, pl;
            #pragma unroll
            for (int p = 0; p < 4; ++p) {
                const float q0 = ha[2 * p]     * aa[2 * p];
                const float q1 = ha[2 * p + 1] * aa[2 * p + 1];
                const uint32_t b0 = __float_as_uint(q0) & 0xffff0000u;
                const uint32_t b1 = __float_as_uint(q1) & 0xffff0000u;
                ph.u[p] = b1 | (b0 >> 16);
                const float s0 = q0 - __uint_as_float(b0);
                const float s1 = q1 - __uint_as_float(b1);
                pl.u[p] = (__float_as_uint(s1) & 0xffff0000u) | (__float_as_uint(s0) >> 16);
            }
            qh[k] = ph.s;
            ql[k] = pl.s;
        }

        #pragma unroll
        for (int jt = 0; jt < 4; ++jt) {
            const int jrow = 16 * jt + f;       // rows>=50 zeroed in LDS
            const short8 bh = *reinterpret_cast<const short8*>(&Hhi[jrow * HS16 + dofs]);
            const short8 bl = *reinterpret_cast<const short8*>(&Hlo[jrow * HS16 + dofs]);
            #pragma unroll
            for (int k = 0; k < 4; ++k) {
                acc[jt][k] = __builtin_amdgcn_mfma_f32_16x16x32_bf16(qh[k], bh, acc[jt][k], 0, 0, 0);
                acc[jt][k] = __builtin_amdgcn_mfma_f32_16x16x32_bf16(qh[k], bl, acc[jt][k], 0, 0, 0);
                acc[jt][k] = __builtin_amdgcn_mfma_f32_16x16x32_bf16(ql[k], bh, acc[jt][k], 0, 0, 0);
            }
        }
    }

    // ---------------- phase 3 (in-register): select + leaky + mask + softmax ----------------
    // lane holds S[i0+4g+reg][16jt+f] for reg 0..3, jt 0..3
    float s[4][4];                              // [jt][reg]
    #pragma unroll
    for (int jt = 0; jt < 4; ++jt) {
        const int j = 16 * jt + f;
        #pragma unroll
        for (int reg = 0; reg < 4; ++reg) {
            const int ii  = i0 + 4 * g + reg;
            const int iic = (ii < kN) ? ii : (kN - 1);
            int kv = 0;
            if (j < kN) kv = Ad[iic * ADS + j];
            const float x = (kv == 1) ? acc[jt][0][reg]
                          : (kv == 2) ? acc[jt][1][reg]
                          : (kv == 3) ? acc[jt][2][reg]
                          : (kv == 4) ? acc[jt][3][reg] : 0.f;
            const float lx = (x > 0.f) ? x : kSlope * x;
            s[jt][reg] = (kv >= 1 && kv <= 4) ? lx : kNeg;
        }
    }

    #pragma unroll
    for (int reg = 0; reg < 4; ++reg) {
        // row max over 64 j: 3 fmax across jt + butterfly over the 16-lane f-group
        float m = fmaxf(fmaxf(s[0][reg], s[1][reg]), fmaxf(s[2][reg], s[3][reg]));
        #pragma unroll
        for (int o = 1; o < 16; o <<= 1) m = fmaxf(m, __shfl_xor(m, o));

        float e[4];
        float t = 0.f;
        #pragma unroll
        for (int jt = 0; jt < 4; ++jt) {
            const int j = 16 * jt + f;
            e[jt] = (j < kN) ? __expf(s[jt][reg] - m) : 0.f;  // all-masked row -> uniform over 50
            t += e[jt];
        }
        #pragma unroll
        for (int o = 1; o < 16; o <<= 1) t += __shfl_xor(t, o);

        const float inv = 1.0f / t;
        #pragma unroll
        for (int jt = 0; jt < 4; ++jt) {
            uint32_t u = __float_as_uint(e[jt] * inv);
            u += 0x7fffu + ((u >> 16) & 1u);    // bf16 round-to-nearest
            // wave-private transposed P: [j][row-local]; same-wave RAW (lgkmcnt-ordered)
            Pw[wid][(16 * jt + f) * PS + 4 * g + reg] = (unsigned short)(u >> 16);
        }
    }

    // ---------------- phase 4: PV fp32 (v7-proven pattern); lane = (rowquad g, d=4f) ----------------
    #pragma unroll
    for (int dh = 0; dh < 2; ++dh) {
        const int db = 64 * dh + 4 * f;
        f32x4 o0 = {0.f, 0.f, 0.f, 0.f}, o1 = o0, o2 = o0, o3 = o0;
        #pragma unroll 5
        for (int j = 0; j < kN; ++j) {
            const float4  hv = *reinterpret_cast<const float4*>(&Hf[j * HS32 + db]);
            const ushort4 p4 = *reinterpret_cast<const ushort4*>(&Pw[wid][j * PS + 4 * g]);
            const float av0 = __uint_as_float(((uint32_t)p4.x) << 16);
            const float av1 = __uint_as_float(((uint32_t)p4.y) << 16);
            const float av2 = __uint_as_float(((uint32_t)p4.z) << 16);
            const float av3 = __uint_as_float(((uint32_t)p4.w) << 16);
            o0.x += av0 * hv.x; o0.y += av0 * hv.y; o0.z += av0 * hv.z; o0.w += av0 * hv.w;
            o1.x += av1 * hv.x; o1.y += av1 * hv.y; o1.z += av1 * hv.z; o1.w += av1 * hv.w;
            o2.x += av2 * hv.x; o2.y += av2 * hv.y; o2.z += av2 * hv.z; o2.w += av2 * hv.w;
            o3.x += av3 * hv.x; o3.y += av3 * hv.y; o3.z += av3 * hv.z; o3.w += av3 * hv.w;
        }
        const int rbase = i0 + 4 * g;
        if (rbase + 0 < kN) *reinterpret_cast<f32x4*>(&outb[(rbase + 0) * kD + db]) = o0;
        if (rbase + 1 < kN) *reinterpret_cast<f32x4*>(&outb[(rbase + 1) * kD + db]) = o1;
        if (rbase + 2 < kN) *reinterpret_cast<f32x4*>(&outb[(rbase + 2) * kD + db]) = o2;
        if (rbase + 3 < kN) *reinterpret_cast<f32x4*>(&outb[(rbase + 3) * kD + db]) = o3;
    }
}

extern "C" void kernel_launch(void* const* d_in, const int* in_sizes, int n_in,
                              void* d_out, int out_size, void* d_ws, size_t ws_size,
                              hipStream_t stream) {
    const float* hidden = reinterpret_cast<const float*>(d_in[0]);
    const int*   adjp   = reinterpret_cast<const int*>(d_in[1]);
    const float* a0     = reinterpret_cast<const float*>(d_in[2]);
    const float* a1     = reinterpret_cast<const float*>(d_in[3]);
    const float* a2     = reinterpret_cast<const float*>(d_in[4]);
    const float* a3     = reinterpret_cast<const float*>(d_in[5]);
    float*       outp   = reinterpret_cast<float*>(d_out);

    gat_v10_kernel<<<dim3(256), dim3(256), 0, stream>>>(
        hidden, adjp, a0, a1, a2, a3, outp);
}

// Round 11
// 17.758 us; speedup vs baseline: 1.7344x; 1.0324x over previous
//
#include <hip/hip_runtime.h>
#include <stdint.h>

typedef __attribute__((ext_vector_type(8))) short short8;
typedef __attribute__((ext_vector_type(4))) float f32x4;

namespace {
constexpr int   kN     = 50;
constexpr int   kD     = 128;
constexpr float kNeg   = -9.0e15f;
constexpr float kSlope = 0.2f;
constexpr int   HS32   = 132;   // Hf stride (f32)
constexpr int   HS16   = 136;   // Hhi/Hlo stride (shorts)
constexpr int   ADS    = 52;    // adj byte stride
constexpr int   PS     = 20;    // Pw per-j stride (shorts)
}

union Pack8 { uint32_t u[4]; short8 s; };

__global__ __launch_bounds__(512)
void gat_v11_kernel(const float* __restrict__ hidden,
                    const int*   __restrict__ adj,
                    const float* __restrict__ a0,
                    const float* __restrict__ a1,
                    const float* __restrict__ a2,
                    const float* __restrict__ a3,
                    float* __restrict__ out)
{
    __shared__ float          Hf [kN * HS32];    // 26.4 KB f32 H (score A-side + PV)
    __shared__ unsigned short Hhi[64 * HS16];    // 17.4 KB bf16 hi(H), rows>=50 zero
    __shared__ unsigned short Hlo[64 * HS16];    // 17.4 KB bf16 lo(H)
    __shared__ unsigned char  Ad [kN * ADS];     //  2.6 KB adj bytes
    __shared__ float          Xch[8][64][16];    // 32.0 KB K-half partial exchange
    __shared__ unsigned short Pw [8][64 * PS];   // 20.5 KB wave-private P [j][row] bf16
    // total ~114.3 KB -> 1 block/CU, 8 waves = 2 waves/SIMD

    const int b    = blockIdx.x;
    const int tid  = threadIdx.x;
    const int lane = tid & 63;
    const int wid  = __builtin_amdgcn_readfirstlane(tid >> 6);  // 0..7
    const int g    = lane >> 4;
    const int f    = lane & 15;

    const float* __restrict__ hb   = hidden + (size_t)b * (kN * kD);
    const int*   __restrict__ adjb = adj    + (size_t)b * (kN * kN);
    float*       __restrict__ outb = out    + (size_t)b * (kN * kD);

    // ---------------- phase 1: stage Hf + H hi/lo + adj bytes ----------------
    const float4* hg = reinterpret_cast<const float4*>(hb);
    #pragma unroll
    for (int it4 = 0; it4 < 4; ++it4) {
        const int idx = tid + it4 * 512;        // 0..2047 over 64 rows x 32 float4
        const int j   = idx >> 5;
        const int d4  = idx & 31;
        float4 v = make_float4(0.f, 0.f, 0.f, 0.f);
        if (j < kN) v = hg[j * 32 + d4];

        const uint32_t h0 = __float_as_uint(v.x) & 0xffff0000u;
        const uint32_t h1 = __float_as_uint(v.y) & 0xffff0000u;
        const uint32_t h2 = __float_as_uint(v.z) & 0xffff0000u;
        const uint32_t h3 = __float_as_uint(v.w) & 0xffff0000u;
        uint2 hiw;
        hiw.x = h1 | (h0 >> 16);
        hiw.y = h3 | (h2 >> 16);
        const float r0 = v.x - __uint_as_float(h0);
        const float r1 = v.y - __uint_as_float(h1);
        const float r2 = v.z - __uint_as_float(h2);
        const float r3 = v.w - __uint_as_float(h3);
        uint2 low;
        low.x = (__float_as_uint(r1) & 0xffff0000u) | (__float_as_uint(r0) >> 16);
        low.y = (__float_as_uint(r3) & 0xffff0000u) | (__float_as_uint(r2) >> 16);
        *reinterpret_cast<uint2*>(&Hhi[j * HS16 + 4 * d4]) = hiw;
        *reinterpret_cast<uint2*>(&Hlo[j * HS16 + 4 * d4]) = low;
        if (j < kN) *reinterpret_cast<float4*>(&Hf[j * HS32 + 4 * d4]) = v;
    }
    for (int idx = tid; idx < 625; idx += 512) {          // 2500 ints as int4
        const int4 v = reinterpret_cast<const int4*>(adjb)[idx];
        const int e = 4 * idx;
        const int vv[4] = {v.x, v.y, v.z, v.w};
        #pragma unroll
        for (int p = 0; p < 4; ++p) {
            const int ee  = e + p;
            const int row = ee / kN;
            const int col = ee - kN * row;
            Ad[row * ADS + col] = (unsigned char)vv[p];
        }
    }
    __syncthreads();   // barrier #1

    // ---------------- phase 2: scores via MFMA; wave = (i-tile, K-half) ----------------
    const int it   = wid & 3;
    const int kh   = wid >> 2;
    const int i0   = 16 * it;
    const int irow = (i0 + f < kN) ? (i0 + f) : (kN - 1);

    f32x4 acc[4][4];                            // [jt][rel]
    #pragma unroll
    for (int jt = 0; jt < 4; ++jt)
        #pragma unroll
        for (int k = 0; k < 4; ++k) acc[jt][k] = (f32x4){0.f, 0.f, 0.f, 0.f};

    const float* __restrict__ aks[4] = {a0, a1, a2, a3};

    #pragma unroll
    for (int ksl2 = 0; ksl2 < 2; ++ksl2) {
        const int dofs = 64 * kh + 32 * ksl2 + 8 * g;

        const float4 hA0 = *reinterpret_cast<const float4*>(&Hf[irow * HS32 + dofs]);
        const float4 hA1 = *reinterpret_cast<const float4*>(&Hf[irow * HS32 + dofs + 4]);
        const float ha[8] = {hA0.x, hA0.y, hA0.z, hA0.w, hA1.x, hA1.y, hA1.z, hA1.w};

        short8 qh[4], ql[4];
        #pragma unroll
        for (int k = 0; k < 4; ++k) {
            const float4 av0 = *reinterpret_cast<const float4*>(aks[k] + dofs);
            const float4 av1 = *reinterpret_cast<const float4*>(aks[k] + dofs + 4);
            const float aa[8] = {av0.x, av0.y, av0.z, av0.w, av1.x, av1.y, av1.z, av1.w};
            Pack8 ph, pl;
            #pragma unroll
            for (int p = 0; p < 4; ++p) {
                const float q0 = ha[2 * p]     * aa[2 * p];
                const float q1 = ha[2 * p + 1] * aa[2 * p + 1];
                const uint32_t b0 = __float_as_uint(q0) & 0xffff0000u;
                const uint32_t b1 = __float_as_uint(q1) & 0xffff0000u;
                ph.u[p] = b1 | (b0 >> 16);
                const float s0 = q0 - __uint_as_float(b0);
                const float s1 = q1 - __uint_as_float(b1);
                pl.u[p] = (__float_as_uint(s1) & 0xffff0000u) | (__float_as_uint(s0) >> 16);
            }
            qh[k] = ph.s;
            ql[k] = pl.s;
        }

        #pragma unroll
        for (int jt = 0; jt < 4; ++jt) {
            const int jrow = 16 * jt + f;       // rows>=50 zeroed in LDS
            const short8 bh = *reinterpret_cast<const short8*>(&Hhi[jrow * HS16 + dofs]);
            const short8 bl = *reinterpret_cast<const short8*>(&Hlo[jrow * HS16 + dofs]);
            #pragma unroll
            for (int k = 0; k < 4; ++k) {
                acc[jt][k] = __builtin_amdgcn_mfma_f32_16x16x32_bf16(qh[k], bh, acc[jt][k], 0, 0, 0);
                acc[jt][k] = __builtin_amdgcn_mfma_f32_16x16x32_bf16(qh[k], bl, acc[jt][k], 0, 0, 0);
                acc[jt][k] = __builtin_amdgcn_mfma_f32_16x16x32_bf16(ql[k], bh, acc[jt][k], 0, 0, 0);
            }
        }
    }

    // select on K-partial (linear -> commutes with K-sum); build validity mask
    f32x4 spart[4];
    uint32_t vmask = 0;
    #pragma unroll
    for (int jt = 0; jt < 4; ++jt) {
        const int j = 16 * jt + f;
        #pragma unroll
        for (int reg = 0; reg < 4; ++reg) {
            const int ii  = i0 + 4 * g + reg;
            const int iic = (ii < kN) ? ii : (kN - 1);
            int kv = 0;
            if (j < kN) kv = Ad[iic * ADS + j];
            const bool valid = (kv >= 1) && (kv <= 4);
            spart[jt][reg] = (kv == 1) ? acc[jt][0][reg]
                           : (kv == 2) ? acc[jt][1][reg]
                           : (kv == 3) ? acc[jt][2][reg]
                           : (kv == 4) ? acc[jt][3][reg] : 0.f;
            vmask |= (valid ? 1u : 0u) << (4 * jt + reg);
        }
    }

    // pairwise K-half exchange
    #pragma unroll
    for (int jt = 0; jt < 4; ++jt)
        *reinterpret_cast<f32x4*>(&Xch[wid][lane][4 * jt]) = spart[jt];
    __syncthreads();   // barrier #2

    // ---------------- phase 3: sum halves + leaky + mask + in-register softmax ----------------
    float s[4][4];
    #pragma unroll
    for (int jt = 0; jt < 4; ++jt) {
        const f32x4 o = *reinterpret_cast<const f32x4*>(&Xch[wid ^ 4][lane][4 * jt]);
        #pragma unroll
        for (int reg = 0; reg < 4; ++reg) {
            const float x  = spart[jt][reg] + o[reg];
            const float lx = (x > 0.f) ? x : kSlope * x;
            s[jt][reg] = ((vmask >> (4 * jt + reg)) & 1u) ? lx : kNeg;
        }
    }

    #pragma unroll
    for (int reg = 0; reg < 4; ++reg) {
        float m = fmaxf(fmaxf(s[0][reg], s[1][reg]), fmaxf(s[2][reg], s[3][reg]));
        #pragma unroll
        for (int o = 1; o < 16; o <<= 1) m = fmaxf(m, __shfl_xor(m, o));

        float e[4];
        float t = 0.f;
        #pragma unroll
        for (int jt = 0; jt < 4; ++jt) {
            const int j = 16 * jt + f;
            e[jt] = (j < kN) ? __expf(s[jt][reg] - m) : 0.f;  // all-masked -> uniform (matches ref)
            t += e[jt];
        }
        #pragma unroll
        for (int o = 1; o < 16; o <<= 1) t += __shfl_xor(t, o);

        const float inv = 1.0f / t;
        #pragma unroll
        for (int jt = 0; jt < 4; ++jt) {
            uint32_t u = __float_as_uint(e[jt] * inv);
            u += 0x7fffu + ((u >> 16) & 1u);    // bf16 round-to-nearest
            Pw[wid][(16 * jt + f) * PS + 4 * g + reg] = (unsigned short)(u >> 16);
        }
    }

    // ---------------- phase 4: PV fp32; wave handles d-half = kh (same-wave P, no barrier) ----------------
    {
        const int db = 64 * kh + 4 * f;
        f32x4 o0 = {0.f, 0.f, 0.f, 0.f}, o1 = o0, o2 = o0, o3 = o0;
        #pragma unroll 5
        for (int j = 0; j < kN; ++j) {
            const float4  hv = *reinterpret_cast<const float4*>(&Hf[j * HS32 + db]);
            const ushort4 p4 = *reinterpret_cast<const ushort4*>(&Pw[wid][j * PS + 4 * g]);
            const float av0 = __uint_as_float(((uint32_t)p4.x) << 16);
            const float av1 = __uint_as_float(((uint32_t)p4.y) << 16);
            const float av2 = __uint_as_float(((uint32_t)p4.z) << 16);
            const float av3 = __uint_as_float(((uint32_t)p4.w) << 16);
            o0.x += av0 * hv.x; o0.y += av0 * hv.y; o0.z += av0 * hv.z; o0.w += av0 * hv.w;
            o1.x += av1 * hv.x; o1.y += av1 * hv.y; o1.z += av1 * hv.z; o1.w += av1 * hv.w;
            o2.x += av2 * hv.x; o2.y += av2 * hv.y; o2.z += av2 * hv.z; o2.w += av2 * hv.w;
            o3.x += av3 * hv.x; o3.y += av3 * hv.y; o3.z += av3 * hv.z; o3.w += av3 * hv.w;
        }
        const int rbase = i0 + 4 * g;
        if (rbase + 0 < kN) *reinterpret_cast<f32x4*>(&outb[(rbase + 0) * kD + db]) = o0;
        if (rbase + 1 < kN) *reinterpret_cast<f32x4*>(&outb[(rbase + 1) * kD + db]) = o1;
        if (rbase + 2 < kN) *reinterpret_cast<f32x4*>(&outb[(rbase + 2) * kD + db]) = o2;
        if (rbase + 3 < kN) *reinterpret_cast<f32x4*>(&outb[(rbase + 3) * kD + db]) = o3;
    }
}

extern "C" void kernel_launch(void* const* d_in, const int* in_sizes, int n_in,
                              void* d_out, int out_size, void* d_ws, size_t ws_size,
                              hipStream_t stream) {
    const float* hidden = reinterpret_cast<const float*>(d_in[0]);
    const int*   adjp   = reinterpret_cast<const int*>(d_in[1]);
    const float* a0     = reinterpret_cast<const float*>(d_in[2]);
    const float* a1     = reinterpret_cast<const float*>(d_in[3]);
    const float* a2     = reinterpret_cast<const float*>(d_in[4]);
    const float* a3     = reinterpret_cast<const float*>(d_in[5]);
    float*       outp   = reinterpret_cast<float*>(d_out);

    gat_v11_kernel<<<dim3(256), dim3(512), 0, stream>>>(
        hidden, adjp, a0, a1, a2, a3, outp);
}

// Round 12
// 16.981 us; speedup vs baseline: 1.8137x; 1.0457x over previous
//
#include <hip/hip_runtime.h>
#include <stdint.h>

typedef __attribute__((ext_vector_type(8))) short short8;
typedef __attribute__((ext_vector_type(4))) float f32x4;

namespace {
constexpr int   kN     = 50;
constexpr int   kD     = 128;
constexpr float kNeg   = -9.0e15f;
constexpr float kSlope = 0.2f;
constexpr int   HS16   = 136;   // Hhi/Hlo row stride (shorts), 16B-aligned rows
constexpr int   ADS    = 52;    // adj byte stride
constexpr int   HTW    = 66;    // Hti row stride (u32 words): 264B rows, 8B-aligned
constexpr int   PW     = 72;    // Pw2 row stride (shorts): 144B rows, 16B-aligned
}

union Pack8 { uint32_t u[4]; short8 s; };

// interleaved hi|lo bf16 pack: low short = hi-bf16(v), high short = lo-bf16(v - hi)
__device__ __forceinline__ uint32_t pack_hl(float v) {
    const uint32_t b  = __float_as_uint(v);
    const uint32_t hi = b & 0xffff0000u;
    const float    r  = v - __uint_as_float(hi);
    return (b >> 16) | (__float_as_uint(r) & 0xffff0000u);
}

__global__ __launch_bounds__(512)
void gat_v12_kernel(const float* __restrict__ hidden,
                    const int*   __restrict__ adj,
                    const float* __restrict__ a0,
                    const float* __restrict__ a1,
                    const float* __restrict__ a2,
                    const float* __restrict__ a3,
                    float* __restrict__ out)
{
    __shared__ unsigned short Hhi[64 * HS16];   // 17.0 KB bf16 hi(H) rows, j>=50 zero
    __shared__ unsigned short Hlo[64 * HS16];   // 17.0 KB bf16 lo(H)
    __shared__ uint32_t       Hti[128 * HTW];   // 33.0 KB transposed H [d][j], hi|lo interleaved
    __shared__ unsigned char  Ad [kN * ADS];    //  2.5 KB adj bytes
    __shared__ float          Xch[8][64][16];   // 32.0 KB K-half partial exchange
    __shared__ unsigned short Pw2[8][16 * PW];  // 18.0 KB per-wave P [i][j] bf16
    // total ~120 KB -> 1 block/CU, 8 waves

    const int b    = blockIdx.x;
    const int tid  = threadIdx.x;
    const int lane = tid & 63;
    const int wid  = __builtin_amdgcn_readfirstlane(tid >> 6);  // 0..7
    const int g    = lane >> 4;
    const int f    = lane & 15;

    const float* __restrict__ hb   = hidden + (size_t)b * (kN * kD);
    const int*   __restrict__ adjb = adj    + (size_t)b * (kN * kN);
    float*       __restrict__ outb = out    + (size_t)b * (kN * kD);

    // ---------------- phase 1a: stage H hi/lo rows (v11-proven) ----------------
    const float4* hg = reinterpret_cast<const float4*>(hb);
    #pragma unroll
    for (int it4 = 0; it4 < 4; ++it4) {
        const int idx = tid + it4 * 512;        // 0..2047 over 64 rows x 32 float4
        const int j   = idx >> 5;
        const int d4  = idx & 31;
        float4 v = make_float4(0.f, 0.f, 0.f, 0.f);
        if (j < kN) v = hg[j * 32 + d4];

        const uint32_t h0 = __float_as_uint(v.x) & 0xffff0000u;
        const uint32_t h1 = __float_as_uint(v.y) & 0xffff0000u;
        const uint32_t h2 = __float_as_uint(v.z) & 0xffff0000u;
        const uint32_t h3 = __float_as_uint(v.w) & 0xffff0000u;
        uint2 hiw;
        hiw.x = h1 | (h0 >> 16);
        hiw.y = h3 | (h2 >> 16);
        const float r0 = v.x - __uint_as_float(h0);
        const float r1 = v.y - __uint_as_float(h1);
        const float r2 = v.z - __uint_as_float(h2);
        const float r3 = v.w - __uint_as_float(h3);
        uint2 low;
        low.x = (__float_as_uint(r1) & 0xffff0000u) | (__float_as_uint(r0) >> 16);
        low.y = (__float_as_uint(r3) & 0xffff0000u) | (__float_as_uint(r2) >> 16);
        *reinterpret_cast<uint2*>(&Hhi[j * HS16 + 4 * d4]) = hiw;
        *reinterpret_cast<uint2*>(&Hlo[j * HS16 + 4 * d4]) = low;
    }
    // ---------------- phase 1b: adj bytes ----------------
    for (int idx = tid; idx < 625; idx += 512) {          // 2500 ints as int4
        const int4 v = reinterpret_cast<const int4*>(adjb)[idx];
        const int e = 4 * idx;
        const int vv[4] = {v.x, v.y, v.z, v.w};
        #pragma unroll
        for (int p = 0; p < 4; ++p) {
            const int ee  = e + p;
            const int row = ee / kN;
            const int col = ee - kN * row;
            Ad[row * ADS + col] = (unsigned char)vv[p];
        }
    }
    // ---------------- phase 1c: transposed interleaved Hti[d][j] ----------------
    const float2* hb2 = reinterpret_cast<const float2*>(hb);
    #pragma unroll
    for (int it4 = 0; it4 < 4; ++it4) {
        const int jp = wid + 8 * it4;           // 0..31 j-pairs
        const int j0 = 2 * jp, j1 = 2 * jp + 1;
        const int d2 = lane;                    // 0..63 d-pairs
        float2 v0 = make_float2(0.f, 0.f), v1 = v0;
        if (j0 < kN) v0 = hb2[j0 * 64 + d2];    // L1-hot (re-read of 1a data)
        if (j1 < kN) v1 = hb2[j1 * 64 + d2];
        uint2 wa, wb;
        wa.x = pack_hl(v0.x); wa.y = pack_hl(v1.x);   // row d=2d2, cols j0,j1
        wb.x = pack_hl(v0.y); wb.y = pack_hl(v1.y);   // row d=2d2+1
        *reinterpret_cast<uint2*>(&Hti[(2 * d2 + 0) * HTW + j0]) = wa;
        *reinterpret_cast<uint2*>(&Hti[(2 * d2 + 1) * HTW + j0]) = wb;
    }
    __syncthreads();   // barrier #1

    // ---------------- phase 2: scores via MFMA; wave = (i-tile, K-half) ----------------
    const int it   = wid & 3;
    const int kh   = wid >> 2;
    const int i0   = 16 * it;
    const int irow = (i0 + f < kN) ? (i0 + f) : (kN - 1);

    f32x4 acc[4][4];                            // [jt][rel]
    #pragma unroll
    for (int jt = 0; jt < 4; ++jt)
        #pragma unroll
        for (int k = 0; k < 4; ++k) acc[jt][k] = (f32x4){0.f, 0.f, 0.f, 0.f};

    const float* __restrict__ aks[4] = {a0, a1, a2, a3};

    #pragma unroll
    for (int ksl2 = 0; ksl2 < 2; ++ksl2) {
        const int dofs = 64 * kh + 32 * ksl2 + 8 * g;

        // A-side h_i reconstructed from Hhi+Hlo (v6-proven; Hf dropped)
        const short8 ah8 = *reinterpret_cast<const short8*>(&Hhi[irow * HS16 + dofs]);
        const short8 al8 = *reinterpret_cast<const short8*>(&Hlo[irow * HS16 + dofs]);
        float ha[8];
        #pragma unroll
        for (int p = 0; p < 8; ++p) {
            const uint32_t uh = ((uint32_t)(unsigned short)ah8[p]) << 16;
            const uint32_t ul = ((uint32_t)(unsigned short)al8[p]) << 16;
            ha[p] = __uint_as_float(uh) + __uint_as_float(ul);
        }

        short8 qh[4], ql[4];
        #pragma unroll
        for (int k = 0; k < 4; ++k) {
            const float4 av0 = *reinterpret_cast<const float4*>(aks[k] + dofs);
            const float4 av1 = *reinterpret_cast<const float4*>(aks[k] + dofs + 4);
            const float aa[8] = {av0.x, av0.y, av0.z, av0.w, av1.x, av1.y, av1.z, av1.w};
            Pack8 ph, pl;
            #pragma unroll
            for (int p = 0; p < 4; ++p) {
                const float q0 = ha[2 * p]     * aa[2 * p];
                const float q1 = ha[2 * p + 1] * aa[2 * p + 1];
                const uint32_t b0 = __float_as_uint(q0) & 0xffff0000u;
                const uint32_t b1 = __float_as_uint(q1) & 0xffff0000u;
                ph.u[p] = b1 | (b0 >> 16);
                const float s0 = q0 - __uint_as_float(b0);
                const float s1 = q1 - __uint_as_float(b1);
                pl.u[p] = (__float_as_uint(s1) & 0xffff0000u) | (__float_as_uint(s0) >> 16);
            }
            qh[k] = ph.s;
            ql[k] = pl.s;
        }

        #pragma unroll
        for (int jt = 0; jt < 4; ++jt) {
            const int jrow = 16 * jt + f;       // rows>=50 zeroed in LDS
            const short8 bh = *reinterpret_cast<const short8*>(&Hhi[jrow * HS16 + dofs]);
            const short8 bl = *reinterpret_cast<const short8*>(&Hlo[jrow * HS16 + dofs]);
            #pragma unroll
            for (int k = 0; k < 4; ++k) {
                acc[jt][k] = __builtin_amdgcn_mfma_f32_16x16x32_bf16(qh[k], bh, acc[jt][k], 0, 0, 0);
                acc[jt][k] = __builtin_amdgcn_mfma_f32_16x16x32_bf16(qh[k], bl, acc[jt][k], 0, 0, 0);
                acc[jt][k] = __builtin_amdgcn_mfma_f32_16x16x32_bf16(ql[k], bh, acc[jt][k], 0, 0, 0);
            }
        }
    }

    // select on K-partial (linear -> commutes with K-sum); build validity mask
    f32x4 spart[4];
    uint32_t vmask = 0;
    #pragma unroll
    for (int jt = 0; jt < 4; ++jt) {
        const int j = 16 * jt + f;
        #pragma unroll
        for (int reg = 0; reg < 4; ++reg) {
            const int ii  = i0 + 4 * g + reg;
            const int iic = (ii < kN) ? ii : (kN - 1);
            int kv = 0;
            if (j < kN) kv = Ad[iic * ADS + j];
            const bool valid = (kv >= 1) && (kv <= 4);
            spart[jt][reg] = (kv == 1) ? acc[jt][0][reg]
                           : (kv == 2) ? acc[jt][1][reg]
                           : (kv == 3) ? acc[jt][2][reg]
                           : (kv == 4) ? acc[jt][3][reg] : 0.f;
            vmask |= (valid ? 1u : 0u) << (4 * jt + reg);
        }
    }

    // pairwise K-half exchange
    #pragma unroll
    for (int jt = 0; jt < 4; ++jt)
        *reinterpret_cast<f32x4*>(&Xch[wid][lane][4 * jt]) = spart[jt];
    __syncthreads();   // barrier #2

    // ---------------- phase 3: sum halves + leaky + mask + in-register softmax ----------------
    float s[4][4];
    #pragma unroll
    for (int jt = 0; jt < 4; ++jt) {
        const f32x4 o = *reinterpret_cast<const f32x4*>(&Xch[wid ^ 4][lane][4 * jt]);
        #pragma unroll
        for (int reg = 0; reg < 4; ++reg) {
            const float x  = spart[jt][reg] + o[reg];
            const float lx = (x > 0.f) ? x : kSlope * x;
            s[jt][reg] = ((vmask >> (4 * jt + reg)) & 1u) ? lx : kNeg;
        }
    }

    #pragma unroll
    for (int reg = 0; reg < 4; ++reg) {
        float m = fmaxf(fmaxf(s[0][reg], s[1][reg]), fmaxf(s[2][reg], s[3][reg]));
        #pragma unroll
        for (int o = 1; o < 16; o <<= 1) m = fmaxf(m, __shfl_xor(m, o));

        float e[4];
        float t = 0.f;
        #pragma unroll
        for (int jt = 0; jt < 4; ++jt) {
            const int j = 16 * jt + f;
            e[jt] = (j < kN) ? __expf(s[jt][reg] - m) : 0.f;  // all-masked -> uniform (matches ref)
            t += e[jt];
        }
        #pragma unroll
        for (int o = 1; o < 16; o <<= 1) t += __shfl_xor(t, o);

        const float inv = 1.0f / t;
        #pragma unroll
        for (int jt = 0; jt < 4; ++jt) {
            uint32_t u = __float_as_uint(e[jt] * inv);
            u += 0x7fffu + ((u >> 16) & 1u);    // bf16 round-to-nearest
            // P in [i][j] layout -> A-frag-ready rows (same-wave RAW, lgkmcnt-ordered)
            Pw2[wid][(4 * g + reg) * PW + 16 * jt + f] = (unsigned short)(u >> 16);
        }
    }

    // ---------------- phase 4: PV via MFMA; wave handles d-half = kh ----------------
    {
        const int db = 64 * kh;

        // A-frags: P[i=f][j=8g+p (+32jc)] -- one b128 each
        const short8 af0 = *reinterpret_cast<const short8*>(&Pw2[wid][f * PW + 0  + 8 * g]);
        const short8 af1 = *reinterpret_cast<const short8*>(&Pw2[wid][f * PW + 32 + 8 * g]);

        f32x4 acc2[4];
        #pragma unroll
        for (int dt = 0; dt < 4; ++dt) acc2[dt] = (f32x4){0.f, 0.f, 0.f, 0.f};

        #pragma unroll
        for (int dt = 0; dt < 4; ++dt) {
            const int drow = db + 16 * dt + f;
            #pragma unroll
            for (int jc = 0; jc < 2; ++jc) {
                const uint32_t* hp = &Hti[drow * HTW + 32 * jc + 8 * g];
                const uint2 u01 = *reinterpret_cast<const uint2*>(hp + 0);
                const uint2 u23 = *reinterpret_cast<const uint2*>(hp + 2);
                const uint2 u45 = *reinterpret_cast<const uint2*>(hp + 4);
                const uint2 u67 = *reinterpret_cast<const uint2*>(hp + 6);
                Pack8 bh, bl;
                bh.u[0] = (u01.x & 0xffffu) | (u01.y << 16);
                bl.u[0] = (u01.x >> 16)     | (u01.y & 0xffff0000u);
                bh.u[1] = (u23.x & 0xffffu) | (u23.y << 16);
                bl.u[1] = (u23.x >> 16)     | (u23.y & 0xffff0000u);
                bh.u[2] = (u45.x & 0xffffu) | (u45.y << 16);
                bl.u[2] = (u45.x >> 16)     | (u45.y & 0xffff0000u);
                bh.u[3] = (u67.x & 0xffffu) | (u67.y << 16);
                bl.u[3] = (u67.x >> 16)     | (u67.y & 0xffff0000u);
                const short8 a8 = jc ? af1 : af0;
                acc2[dt] = __builtin_amdgcn_mfma_f32_16x16x32_bf16(a8, bh.s, acc2[dt], 0, 0, 0);
                acc2[dt] = __builtin_amdgcn_mfma_f32_16x16x32_bf16(a8, bl.s, acc2[dt], 0, 0, 0);
            }
        }

        // stores: D[row=4g+reg -> i][col=f -> d]; coalesced 64B segments per (dt,reg)
        #pragma unroll
        for (int reg = 0; reg < 4; ++reg) {
            const int ii = 16 * it + 4 * g + reg;
            if (ii < kN) {
                #pragma unroll
                for (int dt = 0; dt < 4; ++dt)
                    outb[ii * kD + db + 16 * dt + f] = acc2[dt][reg];
            }
        }
    }
}

extern "C" void kernel_launch(void* const* d_in, const int* in_sizes, int n_in,
                              void* d_out, int out_size, void* d_ws, size_t ws_size,
                              hipStream_t stream) {
    const float* hidden = reinterpret_cast<const float*>(d_in[0]);
    const int*   adjp   = reinterpret_cast<const int*>(d_in[1]);
    const float* a0     = reinterpret_cast<const float*>(d_in[2]);
    const float* a1     = reinterpret_cast<const float*>(d_in[3]);
    const float* a2     = reinterpret_cast<const float*>(d_in[4]);
    const float* a3     = reinterpret_cast<const float*>(d_in[5]);
    float*       outp   = reinterpret_cast<float*>(d_out);

    gat_v12_kernel<<<dim3(256), dim3(512), 0, stream>>>(
        hidden, adjp, a0, a1, a2, a3, outp);
}

// Round 13
// 16.080 us; speedup vs baseline: 1.9153x; 1.0560x over previous
//
#include <hip/hip_runtime.h>
#include <stdint.h>

typedef __attribute__((ext_vector_type(8))) short short8;
typedef __attribute__((ext_vector_type(4))) float f32x4;

namespace {
constexpr int   kN     = 50;
constexpr int   kD     = 128;
constexpr float kNeg   = -9.0e15f;
constexpr float kSlope = 0.2f;
constexpr int   HS16   = 136;   // Hhi/Hlo row stride (shorts), 16B-aligned rows
constexpr int   ADS    = 52;    // adj byte stride
constexpr int   HTW    = 66;    // Hti row stride (u32 words): 264B rows, 8B-aligned
constexpr int   PW     = 72;    // Pw2 row stride (shorts): 144B rows, 16B-aligned
}

union Pack8 { uint32_t u[4]; short8 s; };

// interleaved hi|lo bf16 pack: low short = hi-bf16(v), high short = lo-bf16(v - hi)
__device__ __forceinline__ uint32_t pack_hl(float v) {
    const uint32_t b  = __float_as_uint(v);
    const uint32_t hi = b & 0xffff0000u;
    const float    r  = v - __uint_as_float(hi);
    return (b >> 16) | (__float_as_uint(r) & 0xffff0000u);
}

__global__ __launch_bounds__(512)
void gat_v13_kernel(const float* __restrict__ hidden,
                    const int*   __restrict__ adj,
                    const float* __restrict__ a0,
                    const float* __restrict__ a1,
                    const float* __restrict__ a2,
                    const float* __restrict__ a3,
                    float* __restrict__ out)
{
    __shared__ unsigned short Hhi[64 * HS16];   // 17.0 KB bf16 hi(H) rows, j>=50 zero
    __shared__ unsigned short Hlo[64 * HS16];   // 17.0 KB bf16 lo(H)
    __shared__ uint32_t       Hti[128 * HTW];   // 33.0 KB transposed H [d][j], hi|lo interleaved
    __shared__ unsigned char  Ad [kN * ADS];    //  2.5 KB adj bytes
    __shared__ float          Xch[8][64][16];   // 32.0 KB K-half partial exchange
    __shared__ unsigned short Pw2[8][16 * PW];  // 18.0 KB per-wave P [i][j] bf16
    // total ~120 KB -> 1 block/CU, 8 waves

    const int b    = blockIdx.x;
    const int tid  = threadIdx.x;
    const int lane = tid & 63;
    const int wid  = __builtin_amdgcn_readfirstlane(tid >> 6);  // 0..7
    const int g    = lane >> 4;
    const int f    = lane & 15;

    const float* __restrict__ hb   = hidden + (size_t)b * (kN * kD);
    const int*   __restrict__ adjb = adj    + (size_t)b * (kN * kN);
    float*       __restrict__ outb = out    + (size_t)b * (kN * kD);

    // ---------------- phase 1a: stage H hi/lo rows ----------------
    const float4* hg = reinterpret_cast<const float4*>(hb);
    #pragma unroll
    for (int it4 = 0; it4 < 4; ++it4) {
        const int idx = tid + it4 * 512;        // 0..2047 over 64 rows x 32 float4
        const int j   = idx >> 5;
        const int d4  = idx & 31;
        float4 v = make_float4(0.f, 0.f, 0.f, 0.f);
        if (j < kN) v = hg[j * 32 + d4];

        const uint32_t h0 = __float_as_uint(v.x) & 0xffff0000u;
        const uint32_t h1 = __float_as_uint(v.y) & 0xffff0000u;
        const uint32_t h2 = __float_as_uint(v.z) & 0xffff0000u;
        const uint32_t h3 = __float_as_uint(v.w) & 0xffff0000u;
        uint2 hiw;
        hiw.x = h1 | (h0 >> 16);
        hiw.y = h3 | (h2 >> 16);
        const float r0 = v.x - __uint_as_float(h0);
        const float r1 = v.y - __uint_as_float(h1);
        const float r2 = v.z - __uint_as_float(h2);
        const float r3 = v.w - __uint_as_float(h3);
        uint2 low;
        low.x = (__float_as_uint(r1) & 0xffff0000u) | (__float_as_uint(r0) >> 16);
        low.y = (__float_as_uint(r3) & 0xffff0000u) | (__float_as_uint(r2) >> 16);
        *reinterpret_cast<uint2*>(&Hhi[j * HS16 + 4 * d4]) = hiw;
        *reinterpret_cast<uint2*>(&Hlo[j * HS16 + 4 * d4]) = low;
    }
    // ---------------- phase 1b: adj bytes ----------------
    for (int idx = tid; idx < 625; idx += 512) {          // 2500 ints as int4
        const int4 v = reinterpret_cast<const int4*>(adjb)[idx];
        const int e = 4 * idx;
        const int vv[4] = {v.x, v.y, v.z, v.w};
        #pragma unroll
        for (int p = 0; p < 4; ++p) {
            const int ee  = e + p;
            const int row = ee / kN;
            const int col = ee - kN * row;
            Ad[row * ADS + col] = (unsigned char)vv[p];
        }
    }
    // ---------------- phase 1c (T14 issue-early): H transpose source -> registers ----------------
    const float2* hb2 = reinterpret_cast<const float2*>(hb);
    float2 tv0[4], tv1[4];
    #pragma unroll
    for (int it4 = 0; it4 < 4; ++it4) {
        const int jp = wid + 8 * it4;           // 0..31 j-pairs
        const int j0 = 2 * jp, j1 = 2 * jp + 1;
        tv0[it4] = (j0 < kN) ? hb2[j0 * 64 + lane] : make_float2(0.f, 0.f);
        tv1[it4] = (j1 < kN) ? hb2[j1 * 64 + lane] : make_float2(0.f, 0.f);
    }
    __syncthreads();   // barrier #1

    // ---------------- phase 2: scores via MFMA; wave = (i-tile, K-half) ----------------
    const int it   = wid & 3;
    const int kh   = wid >> 2;
    const int i0   = 16 * it;
    const int irow = (i0 + f < kN) ? (i0 + f) : (kN - 1);

    // adj bytes for this wave's 16x16x4 footprint -> registers (overlaps score loop)
    int adv[4][4];
    #pragma unroll
    for (int jt = 0; jt < 4; ++jt) {
        const int j = 16 * jt + f;
        #pragma unroll
        for (int reg = 0; reg < 4; ++reg) {
            const int ii  = i0 + 4 * g + reg;
            const int iic = (ii < kN) ? ii : (kN - 1);
            adv[jt][reg] = (j < kN) ? (int)Ad[iic * ADS + j] : 0;
        }
    }

    f32x4 acc[4][4];                            // [jt][rel]
    #pragma unroll
    for (int jt = 0; jt < 4; ++jt)
        #pragma unroll
        for (int k = 0; k < 4; ++k) acc[jt][k] = (f32x4){0.f, 0.f, 0.f, 0.f};

    const float* __restrict__ aks[4] = {a0, a1, a2, a3};

    #pragma unroll
    for (int ksl2 = 0; ksl2 < 2; ++ksl2) {
        const int dofs = 64 * kh + 32 * ksl2 + 8 * g;

        // A-side h_i reconstructed from Hhi+Hlo
        const short8 ah8 = *reinterpret_cast<const short8*>(&Hhi[irow * HS16 + dofs]);
        const short8 al8 = *reinterpret_cast<const short8*>(&Hlo[irow * HS16 + dofs]);
        float ha[8];
        #pragma unroll
        for (int p = 0; p < 8; ++p) {
            const uint32_t uh = ((uint32_t)(unsigned short)ah8[p]) << 16;
            const uint32_t ul = ((uint32_t)(unsigned short)al8[p]) << 16;
            ha[p] = __uint_as_float(uh) + __uint_as_float(ul);
        }

        short8 qh[4], ql[4];
        #pragma unroll
        for (int k = 0; k < 4; ++k) {
            const float4 av0 = *reinterpret_cast<const float4*>(aks[k] + dofs);
            const float4 av1 = *reinterpret_cast<const float4*>(aks[k] + dofs + 4);
            const float aa[8] = {av0.x, av0.y, av0.z, av0.w, av1.x, av1.y, av1.z, av1.w};
            Pack8 ph, pl;
            #pragma unroll
            for (int p = 0; p < 4; ++p) {
                const float q0 = ha[2 * p]     * aa[2 * p];
                const float q1 = ha[2 * p + 1] * aa[2 * p + 1];
                const uint32_t b0 = __float_as_uint(q0) & 0xffff0000u;
                const uint32_t b1 = __float_as_uint(q1) & 0xffff0000u;
                ph.u[p] = b1 | (b0 >> 16);
                const float s0 = q0 - __uint_as_float(b0);
                const float s1 = q1 - __uint_as_float(b1);
                pl.u[p] = (__float_as_uint(s1) & 0xffff0000u) | (__float_as_uint(s0) >> 16);
            }
            qh[k] = ph.s;
            ql[k] = pl.s;
        }

        #pragma unroll
        for (int jt = 0; jt < 4; ++jt) {
            const int jrow = 16 * jt + f;       // rows>=50 zeroed in LDS
            const short8 bh = *reinterpret_cast<const short8*>(&Hhi[jrow * HS16 + dofs]);
            const short8 bl = *reinterpret_cast<const short8*>(&Hlo[jrow * HS16 + dofs]);
            #pragma unroll
            for (int k = 0; k < 4; ++k) {
                acc[jt][k] = __builtin_amdgcn_mfma_f32_16x16x32_bf16(qh[k], bh, acc[jt][k], 0, 0, 0);
                acc[jt][k] = __builtin_amdgcn_mfma_f32_16x16x32_bf16(qh[k], bl, acc[jt][k], 0, 0, 0);
                acc[jt][k] = __builtin_amdgcn_mfma_f32_16x16x32_bf16(ql[k], bh, acc[jt][k], 0, 0, 0);
            }
        }
    }

    // select on K-partial (linear -> commutes with K-sum) using register adj
    f32x4 spart[4];
    uint32_t vmask = 0;
    #pragma unroll
    for (int jt = 0; jt < 4; ++jt) {
        #pragma unroll
        for (int reg = 0; reg < 4; ++reg) {
            const int kv = adv[jt][reg];
            const bool valid = (kv >= 1) && (kv <= 4);
            spart[jt][reg] = (kv == 1) ? acc[jt][0][reg]
                           : (kv == 2) ? acc[jt][1][reg]
                           : (kv == 3) ? acc[jt][2][reg]
                           : (kv == 4) ? acc[jt][3][reg] : 0.f;
            vmask |= (valid ? 1u : 0u) << (4 * jt + reg);
        }
    }

    // ---------------- phase 1c (T14 write-late): pack + LDS-write Hti under barrier #2 ----------------
    #pragma unroll
    for (int it4 = 0; it4 < 4; ++it4) {
        const int jp = wid + 8 * it4;
        const int j0 = 2 * jp;
        const int d2 = lane;
        uint2 wa, wb;
        wa.x = pack_hl(tv0[it4].x); wa.y = pack_hl(tv1[it4].x);   // row d=2d2, cols j0,j0+1
        wb.x = pack_hl(tv0[it4].y); wb.y = pack_hl(tv1[it4].y);   // row d=2d2+1
        *reinterpret_cast<uint2*>(&Hti[(2 * d2 + 0) * HTW + j0]) = wa;
        *reinterpret_cast<uint2*>(&Hti[(2 * d2 + 1) * HTW + j0]) = wb;
    }

    // pairwise K-half exchange
    #pragma unroll
    for (int jt = 0; jt < 4; ++jt)
        *reinterpret_cast<f32x4*>(&Xch[wid][lane][4 * jt]) = spart[jt];
    __syncthreads();   // barrier #2 (orders Xch AND Hti for everyone)

    // ---------------- phase 3: sum halves + leaky + mask + in-register softmax ----------------
    float s[4][4];
    #pragma unroll
    for (int jt = 0; jt < 4; ++jt) {
        const f32x4 o = *reinterpret_cast<const f32x4*>(&Xch[wid ^ 4][lane][4 * jt]);
        #pragma unroll
        for (int reg = 0; reg < 4; ++reg) {
            const float x  = spart[jt][reg] + o[reg];
            const float lx = (x > 0.f) ? x : kSlope * x;
            s[jt][reg] = ((vmask >> (4 * jt + reg)) & 1u) ? lx : kNeg;
        }
    }

    #pragma unroll
    for (int reg = 0; reg < 4; ++reg) {
        float m = fmaxf(fmaxf(s[0][reg], s[1][reg]), fmaxf(s[2][reg], s[3][reg]));
        #pragma unroll
        for (int o = 1; o < 16; o <<= 1) m = fmaxf(m, __shfl_xor(m, o));

        float e[4];
        float t = 0.f;
        #pragma unroll
        for (int jt = 0; jt < 4; ++jt) {
            const int j = 16 * jt + f;
            e[jt] = (j < kN) ? __expf(s[jt][reg] - m) : 0.f;  // all-masked -> uniform (matches ref)
            t += e[jt];
        }
        #pragma unroll
        for (int o = 1; o < 16; o <<= 1) t += __shfl_xor(t, o);

        const float inv = 1.0f / t;
        #pragma unroll
        for (int jt = 0; jt < 4; ++jt) {
            uint32_t u = __float_as_uint(e[jt] * inv);
            u += 0x7fffu + ((u >> 16) & 1u);    // bf16 round-to-nearest
            // P in [i][j] layout -> A-frag-ready rows (same-wave RAW, lgkmcnt-ordered)
            Pw2[wid][(4 * g + reg) * PW + 16 * jt + f] = (unsigned short)(u >> 16);
        }
    }

    // ---------------- phase 4: PV via MFMA; wave handles d-half = kh ----------------
    {
        const int db = 64 * kh;

        // A-frags: P[i=f][j=8g+p (+32jc)] -- one b128 each
        const short8 af0 = *reinterpret_cast<const short8*>(&Pw2[wid][f * PW + 0  + 8 * g]);
        const short8 af1 = *reinterpret_cast<const short8*>(&Pw2[wid][f * PW + 32 + 8 * g]);

        f32x4 acc2[4];
        #pragma unroll
        for (int dt = 0; dt < 4; ++dt) acc2[dt] = (f32x4){0.f, 0.f, 0.f, 0.f};

        #pragma unroll
        for (int dt = 0; dt < 4; ++dt) {
            const int drow = db + 16 * dt + f;
            #pragma unroll
            for (int jc = 0; jc < 2; ++jc) {
                const uint32_t* hp = &Hti[drow * HTW + 32 * jc + 8 * g];
                const uint2 u01 = *reinterpret_cast<const uint2*>(hp + 0);
                const uint2 u23 = *reinterpret_cast<const uint2*>(hp + 2);
                const uint2 u45 = *reinterpret_cast<const uint2*>(hp + 4);
                const uint2 u67 = *reinterpret_cast<const uint2*>(hp + 6);
                Pack8 bh, bl;
                bh.u[0] = (u01.x & 0xffffu) | (u01.y << 16);
                bl.u[0] = (u01.x >> 16)     | (u01.y & 0xffff0000u);
                bh.u[1] = (u23.x & 0xffffu) | (u23.y << 16);
                bl.u[1] = (u23.x >> 16)     | (u23.y & 0xffff0000u);
                bh.u[2] = (u45.x & 0xffffu) | (u45.y << 16);
                bl.u[2] = (u45.x >> 16)     | (u45.y & 0xffff0000u);
                bh.u[3] = (u67.x & 0xffffu) | (u67.y << 16);
                bl.u[3] = (u67.x >> 16)     | (u67.y & 0xffff0000u);
                const short8 a8 = jc ? af1 : af0;
                acc2[dt] = __builtin_amdgcn_mfma_f32_16x16x32_bf16(a8, bh.s, acc2[dt], 0, 0, 0);
                acc2[dt] = __builtin_amdgcn_mfma_f32_16x16x32_bf16(a8, bl.s, acc2[dt], 0, 0, 0);
            }
        }

        // stores: D[row=4g+reg -> i][col=f -> d]; coalesced 64B segments per (dt,reg)
        #pragma unroll
        for (int reg = 0; reg < 4; ++reg) {
            const int ii = 16 * it + 4 * g + reg;
            if (ii < kN) {
                #pragma unroll
                for (int dt = 0; dt < 4; ++dt)
                    outb[ii * kD + db + 16 * dt + f] = acc2[dt][reg];
            }
        }
    }
}

extern "C" void kernel_launch(void* const* d_in, const int* in_sizes, int n_in,
                              void* d_out, int out_size, void* d_ws, size_t ws_size,
                              hipStream_t stream) {
    const float* hidden = reinterpret_cast<const float*>(d_in[0]);
    const int*   adjp   = reinterpret_cast<const int*>(d_in[1]);
    const float* a0     = reinterpret_cast<const float*>(d_in[2]);
    const float* a1     = reinterpret_cast<const float*>(d_in[3]);
    const float* a2     = reinterpret_cast<const float*>(d_in[4]);
    const float* a3     = reinterpret_cast<const float*>(d_in[5]);
    float*       outp   = reinterpret_cast<float*>(d_out);

    gat_v13_kernel<<<dim3(256), dim3(512), 0, stream>>>(
        hidden, adjp, a0, a1, a2, a3, outp);
}